// Round 2
// baseline (3075.522 us; speedup 1.0000x reference)
//
#include <hip/hip_runtime.h>
#include <math.h>

// Problem constants
#define NRT 24000   // B*N_R
#define NLT 40000   // B*N_L

static __device__ __forceinline__ float sigmoidf_(float x){ return 1.0f/(1.0f+expf(-x)); }

// bijective XCD-aware block swizzle (m204 form); nwg = gridDim.x
static __device__ __forceinline__ int xcd_swz(int bid, int nwg){
  int q = nwg>>3, r = nwg&7, x = bid&7, i = bid>>3;
  return (x<r ? x*(q+1) : r*(q+1)+(x-r)*q) + i;
}

// ---------------- input projection: out[n][c] = feat[n][0..3] @ W[4][64] + b ----------------
__global__ void k_proj(const float* __restrict__ feat, const float* __restrict__ W,
                       const float* __restrict__ bias, float* __restrict__ out, int N){
  int i = blockIdx.x*256 + threadIdx.x;
  if (i >= N*64) return;
  int n = i >> 6, c = i & 63;
  const float* f = feat + n*4;
  out[i] = fmaf(f[0], W[c], fmaf(f[1], W[64+c], fmaf(f[2], W[128+c], fmaf(f[3], W[192+c], bias[c]))));
}

// ---------------- per-group (4 voxels) merged neighbor-k bitmask ----------------
__global__ void k_kmask(const int* __restrict__ nbr, int NG, int* __restrict__ kmask){
  int g = blockIdx.x*64 + threadIdx.x;
  if (g >= NG) return;
  int m = 0;
  for (int v=0;v<4;v++){
    const int* row = nbr + (size_t)(g*4+v)*27;
    for (int k=0;k<27;k++) if (row[k] >= 0) m |= (1<<k);
  }
  kmask[g] = m;
}

// ---------------- sparse 27-pt conv, k-merged over groups of 4 voxels ----------------
// out[n][d] = sum_k sum_c f[nbr[n][k]][c] * W[k][c][d]
// (bconv skipped: per-channel constant shift cancels exactly in the following BN)
__global__ void k_sconv(const float* __restrict__ fin, const int* __restrict__ nbr,
                        const int* __restrict__ kmask, const float* __restrict__ W,
                        float* __restrict__ fout, int N){
  int d = threadIdx.x & 63;
  int blk = xcd_swz(blockIdx.x, gridDim.x);
  int g = blk*4 + (threadIdx.x>>6);      // one wave per group of 4 voxels
  int n0 = g*4;
  float acc[4] = {0.f,0.f,0.f,0.f};
  int m = kmask[g];
  while (m){
    int k = __builtin_ctz(m); m &= m-1;
    const float* w = W + k*4096 + d;
    float wr[64];
    #pragma unroll
    for (int c=0;c<64;c++) wr[c] = w[c*64];   // weight column for lane d, held in VGPRs
    #pragma unroll
    for (int v=0;v<4;v++){
      int nb = nbr[(size_t)(n0+v)*27 + k];    // wave-uniform
      if (nb >= 0){
        const float* fr = fin + (size_t)nb*64;
        #pragma unroll
        for (int c=0;c<64;c+=4){
          float4 fv = *reinterpret_cast<const float4*>(fr + c);  // uniform broadcast
          acc[v] = fmaf(fv.x, wr[c+0], acc[v]);
          acc[v] = fmaf(fv.y, wr[c+1], acc[v]);
          acc[v] = fmaf(fv.z, wr[c+2], acc[v]);
          acc[v] = fmaf(fv.w, wr[c+3], acc[v]);
        }
      }
    }
  }
  #pragma unroll
  for (int v=0;v<4;v++) fout[(size_t)(n0+v)*64 + d] = acc[v];
}

// ---------------- per-channel sum/sumsq partials over N rows (deterministic) ----------------
__global__ void k_colsum(const float* __restrict__ f, int N, float* __restrict__ partial){
  int d = threadIdx.x & 63, sub = threadIdx.x >> 6;
  float s=0.f, s2=0.f;
  for (int n = blockIdx.x*4 + sub; n < N; n += 1024){
    float v = f[(size_t)n*64+d];
    s += v; s2 = fmaf(v,v,s2);
  }
  __shared__ float ls[4][64], ls2[4][64];
  ls[sub][d]=s; ls2[sub][d]=s2;
  __syncthreads();
  if (sub==0){
    s  = ls[0][d]+ls[1][d]+ls[2][d]+ls[3][d];
    s2 = ls2[0][d]+ls2[1][d]+ls2[2][d]+ls2[3][d];
    partial[(blockIdx.x*64+d)*2+0]=s;
    partial[(blockIdx.x*64+d)*2+1]=s2;
  }
}

__global__ void k_bnfin(const float* __restrict__ partial, int nblk, float invN,
                        const float* __restrict__ g, const float* __restrict__ b,
                        float* __restrict__ mv){
  int d = threadIdx.x; // 64
  float s=0.f, s2=0.f;
  for (int i=0;i<nblk;i++){ s += partial[(i*64+d)*2]; s2 += partial[(i*64+d)*2+1]; }
  float mean = s*invN;
  float var  = s2*invN - mean*mean;
  float rstd = 1.0f/sqrtf(var + 1e-5f);
  float sc = g[d]*rstd;
  mv[d*2]   = sc;
  mv[d*2+1] = b[d] - mean*sc;
}

__global__ void k_bnrelu(float* __restrict__ f, const float* __restrict__ mv, int total){
  int i = blockIdx.x*256+threadIdx.x;
  if (i>=total) return;
  int c = i & 63;
  float v = fmaf(f[i], mv[c*2], mv[c*2+1]);
  f[i] = v>0.f? v:0.f;
}

// ---------------- imgf[b][c] = sigmoid(img[b] @ Wimg + bimg) ----------------
__global__ void k_imgf(const float* __restrict__ img, const float* __restrict__ Wimg,
                       const float* __restrict__ bimg, float* __restrict__ imgf){
  int t = threadIdx.x; // 128
  int b = t>>6, c = t&63;
  float s = bimg[c];
  const float* ir = img + b*512;
  for (int j=0;j<512;j++) s = fmaf(ir[j], Wimg[j*64+c], s);
  imgf[b*64+c] = sigmoidf_(s);
}

// ---------------- attention + gate, in-place update of fL ----------------
// fused = (sum_k a_k key_k) @ Wval + bval   (softmax weights sum to 1)
__global__ void k_attn(float* __restrict__ fL, const float* __restrict__ fR,
                       const int* __restrict__ knn, const int* __restrict__ coordsL,
                       const float* __restrict__ Wval, const float* __restrict__ bval,
                       const float* __restrict__ Wgate, const float* __restrict__ bgate,
                       const float* __restrict__ imgf, int K){
  __shared__ float keys[64*65];   // padded stride 65 -> conflict-free both axes
  __shared__ float fls[64];
  __shared__ float aw[64];
  __shared__ float wks[64];
  __shared__ float fus[64];
  int n = blockIdx.x, t = threadIdx.x;
  float fl = fL[(size_t)n*64+t];
  fls[t] = fl;
  const int* kn = knn + (size_t)n*K;
  for (int k=0;k<K;k++){
    int r = kn[k];
    keys[k*65+t] = fR[(size_t)r*64+t];
  }
  __syncthreads();
  float s = -1e30f;
  if (t < K){
    const float* kr = keys + t*65;
    float a0 = 0.f;
    #pragma unroll
    for (int c=0;c<64;c++) a0 = fmaf(fls[c], kr[c], a0);
    s = a0;
  }
  float mx = s;
  #pragma unroll
  for (int m=32;m;m>>=1) mx = fmaxf(mx, __shfl_xor(mx, m, 64));
  float e = (t<K) ? expf(s-mx) : 0.f;
  float se = e;
  #pragma unroll
  for (int m=32;m;m>>=1) se += __shfl_xor(se, m, 64);
  aw[t] = e/se;
  __syncthreads();
  float wk = 0.f;
  for (int k=0;k<K;k++) wk = fmaf(aw[k], keys[k*65+t], wk);
  wks[t] = wk;
  __syncthreads();
  float fu = bval[t];
  #pragma unroll
  for (int c=0;c<64;c++) fu = fmaf(wks[c], Wval[c*64+t], fu);
  int bid = coordsL[n*4];
  fu *= imgf[bid*64+t];
  fus[t] = fu;
  __syncthreads();
  float gs = bgate[t];
  #pragma unroll
  for (int c=0;c<64;c++) gs = fmaf(fls[c], Wgate[c*64+t], gs);
  #pragma unroll
  for (int c=0;c<64;c++) gs = fmaf(fus[c], Wgate[(64+c)*64+t], gs);
  float gate = sigmoidf_(gs);
  fL[(size_t)n*64+t] = fl + gate*fu;
}

// ---------------- voxel index grid: grid[b][y][x][z] = row or -1 ----------------
__global__ void k_grid(const int* __restrict__ coords, int N, int* __restrict__ grid){
  int n = blockIdx.x*256+threadIdx.x;
  if (n>=N) return;
  int b=coords[n*4], z=coords[n*4+1], y=coords[n*4+2], x=coords[n*4+3];
  grid[((b*128+y)*128+x)*16+z] = n;
}

// ---------------- compact per-column (b,y,x) voxel lists (deterministic z order) ----------------
__global__ void k_colbuild(const int* __restrict__ grid, int* __restrict__ ccnt,
                           int* __restrict__ cent){
  int col = blockIdx.x*256+threadIdx.x;
  if (col >= 2*128*128) return;
  const int* g = grid + col*16;
  int c=0;
  for (int z=0;z<16;z++){ int v=g[z]; if (v>=0) cent[col*16 + (c++)] = (v<<4)|z; }
  ccnt[col]=c;
}

// ---------------- BEV weight repack: Wt2[ls][q=(dy+1)*3+(dx+1)][z][c][o] = Wbev[ls][c*16+z][o][1-dy][1-dx] ----------------
__global__ void k_wt2(const float* __restrict__ Wbev, float* __restrict__ Wt2){
  int i = blockIdx.x*256+threadIdx.x; // total 4*9*16*64*64 = 2359296
  if (i >= 4*9*16*64*64) return;
  int o = i & 63; int r = i >> 6;
  int c = r & 63; r >>= 6;
  int z = r & 15; r >>= 4;
  int q = r % 9; int ls = r / 9;
  int qy = q/3, qx = q%3;        // qy = dy+1
  int ky = 2-qy, kx = 2-qx;      // = 1-dy, 1-dx
  Wt2[i] = Wbev[(size_t)ls*589824 + (size_t)(c*16+z)*576 + o*9 + ky*3 + kx];
}

// ---------------- sparse BEV conv (gather): one wave per output pixel, thread = out channel ----------------
// (bbev skipped: per-channel constant cancels in the following BN over (b,y,x))
__global__ void k_bev(const float* __restrict__ f, const int* __restrict__ ccnt,
                      const int* __restrict__ cent, const float* __restrict__ Wt2,
                      float* __restrict__ outp){
  int p = xcd_swz(blockIdx.x, gridDim.x);   // 2*128*128, %8==0 -> contiguous chunk per XCD
  int b = p>>14, y = (p>>7)&127, x = p&127;
  int t = threadIdx.x;
  float acc = 0.f;
  #pragma unroll
  for (int q=0;q<9;q++){
    int y2 = y + q/3 - 1, x2 = x + q%3 - 1;
    if ((unsigned)y2 < 128u && (unsigned)x2 < 128u){
      int col = ((b<<7)+y2)*128 + x2;
      int cn = ccnt[col];
      const int* ce = cent + col*16;
      for (int i=0;i<cn;i++){
        int e = ce[i];                       // wave-uniform
        int rid = e>>4, z = e&15;
        const float* fr = f + (size_t)rid*64;
        const float* w = Wt2 + (size_t)(((q<<4)+z)<<12) + t;
        #pragma unroll
        for (int c=0;c<64;c+=4){
          float4 fv = *reinterpret_cast<const float4*>(fr + c);  // uniform broadcast
          acc = fmaf(fv.x, w[(c+0)<<6], acc);
          acc = fmaf(fv.y, w[(c+1)<<6], acc);
          acc = fmaf(fv.z, w[(c+2)<<6], acc);
          acc = fmaf(fv.w, w[(c+3)<<6], acc);
        }
      }
    }
  }
  // out element (b, slab*64 + t, y, x); outp already offset by slab*64*16384
  outp[(size_t)b*(256*16384) + (size_t)t*16384 + (p & 16383)] = acc;
}

// ---------------- BEV BN stats (one block per channel) + apply ----------------
__global__ void k_bevstat(const float* __restrict__ outp, const float* __restrict__ g,
                          const float* __restrict__ b, float* __restrict__ mv){
  int ch = blockIdx.x, t = threadIdx.x; // 64 blocks x 256 threads
  float s=0.f, s2=0.f;
  for (int bb=0;bb<2;bb++){
    const float* base = outp + (size_t)bb*(256*16384) + (size_t)ch*16384;
    for (int p=t;p<16384;p+=256){ float v = base[p]; s+=v; s2=fmaf(v,v,s2); }
  }
  __shared__ float ls[256], ls2[256];
  ls[t]=s; ls2[t]=s2; __syncthreads();
  for (int m=128;m;m>>=1){ if (t<m){ ls[t]+=ls[t+m]; ls2[t]+=ls2[t+m]; } __syncthreads(); }
  if (t==0){
    float mean = ls[0]*(1.0f/32768.0f);
    float var  = ls2[0]*(1.0f/32768.0f) - mean*mean;
    float rstd = 1.0f/sqrtf(var+1e-5f);
    float sc = g[ch]*rstd;
    mv[ch*2]=sc; mv[ch*2+1]=b[ch]-mean*sc;
  }
}

__global__ void k_bevbn(float* __restrict__ outp, const float* __restrict__ mv){
  int i = blockIdx.x*256+threadIdx.x; // 2*64*16384
  if (i >= 2*64*16384) return;
  int bb = i>>20; int r = i & ((1<<20)-1);
  int ch = r>>14; int p = r&16383;
  float* a = outp + (size_t)bb*(256*16384) + (size_t)ch*16384 + p;
  float v = fmaf(*a, mv[ch*2], mv[ch*2+1]);
  *a = v>0.f? v:0.f;
}

extern "C" void kernel_launch(void* const* d_in, const int* in_sizes, int n_in,
                              void* d_out, int out_size, void* d_ws, size_t ws_size,
                              hipStream_t stream){
  const float* featR = (const float*)d_in[0];
  const float* featL = (const float*)d_in[1];
  const float* img   = (const float*)d_in[2];
  const float* Win   = (const float*)d_in[3];
  const float* bin_  = (const float*)d_in[4];
  const float* Wconv = (const float*)d_in[5];
  // d_in[6] bconv: cancels in BN
  const float* bng   = (const float*)d_in[7];
  const float* bnb   = (const float*)d_in[8];
  const float* Wimg  = (const float*)d_in[9];
  const float* bimg  = (const float*)d_in[10];
  const float* Wval  = (const float*)d_in[11];
  const float* bval  = (const float*)d_in[12];
  const float* Wgate = (const float*)d_in[13];
  const float* bgate = (const float*)d_in[14];
  const float* Wbev  = (const float*)d_in[15];
  // d_in[16] bbev: cancels in BN
  const float* bntg  = (const float*)d_in[17];
  const float* bntb  = (const float*)d_in[18];
  const int* nbrR    = (const int*)d_in[19];
  const int* nbrL    = (const int*)d_in[20];
  const int* knn0    = (const int*)d_in[21];
  const int* knn1    = (const int*)d_in[22];
  const int* coordsR = (const int*)d_in[23];
  const int* coordsL = (const int*)d_in[24];
  float* outp = (float*)d_out;

  // workspace carve-out (~53 MB)
  char* w = (char*)d_ws;
  auto alloc = [&](size_t bytes){ char* p = w; w += (bytes + 255) & ~(size_t)255; return p; };
  float* fRa = (float*)alloc((size_t)NRT*64*4);
  float* fRb = (float*)alloc((size_t)NRT*64*4);
  float* fLa = (float*)alloc((size_t)NLT*64*4);
  float* fLb = (float*)alloc((size_t)NLT*64*4);
  int*   gridR = (int*)alloc((size_t)2*128*128*16*4);
  int*   gridL = (int*)alloc((size_t)2*128*128*16*4);
  float* Wt2 = (float*)alloc((size_t)4*9*16*64*64*4);
  float* imgfbuf = (float*)alloc(2*64*4);
  float* partial = (float*)alloc((size_t)256*64*2*4);
  float* mv = (float*)alloc(64*2*4);
  int* kmaskR = (int*)alloc((size_t)(NRT/4)*4);
  int* kmaskL = (int*)alloc((size_t)(NLT/4)*4);
  int* ccntR = (int*)alloc((size_t)2*128*128*4);
  int* ccntL = (int*)alloc((size_t)2*128*128*4);
  int* centR = (int*)alloc((size_t)2*128*128*16*4);
  int* centL = (int*)alloc((size_t)2*128*128*16*4);

  hipMemsetAsync(gridR, 0xFF, (size_t)2*128*128*16*4, stream);
  hipMemsetAsync(gridL, 0xFF, (size_t)2*128*128*16*4, stream);
  k_grid<<<(NRT+255)/256,256,0,stream>>>(coordsR, NRT, gridR);
  k_grid<<<(NLT+255)/256,256,0,stream>>>(coordsL, NLT, gridL);
  k_colbuild<<<(2*128*128+255)/256,256,0,stream>>>(gridR, ccntR, centR);
  k_colbuild<<<(2*128*128+255)/256,256,0,stream>>>(gridL, ccntL, centL);
  k_kmask<<<((NRT/4)+63)/64,64,0,stream>>>(nbrR, NRT/4, kmaskR);
  k_kmask<<<((NLT/4)+63)/64,64,0,stream>>>(nbrL, NLT/4, kmaskL);
  k_wt2<<<(4*9*16*64*64+255)/256,256,0,stream>>>(Wbev, Wt2);

  k_proj<<<(NRT*64+255)/256,256,0,stream>>>(featR, Win,     bin_,    fRa, NRT);
  k_proj<<<(NLT*64+255)/256,256,0,stream>>>(featL, Win+256, bin_+64, fLa, NLT);

  float* fRcur=fRa; float* fRalt=fRb; float* fLcur=fLa; float* fLalt=fLb;
  for (int l=0;l<2;l++){
    // branch R: 3 x (sconv -> BN stats -> bn+relu)
    for (int j=0;j<3;j++){
      const float* Wc = Wconv + (size_t)(((l*2+0)*3+j)*27)*4096;
      k_sconv<<<NRT/16,256,0,stream>>>(fRcur, nbrR, kmaskR, Wc, fRalt, NRT);
      k_colsum<<<256,256,0,stream>>>(fRalt, NRT, partial);
      k_bnfin<<<1,64,0,stream>>>(partial, 256, 1.0f/NRT,
                                 bng + ((l*2+0)*3+j)*64, bnb + ((l*2+0)*3+j)*64, mv);
      k_bnrelu<<<(NRT*64+255)/256,256,0,stream>>>(fRalt, mv, NRT*64);
      float* tmp=fRcur; fRcur=fRalt; fRalt=tmp;
    }
    // branch L
    for (int j=0;j<3;j++){
      const float* Wc = Wconv + (size_t)(((l*2+1)*3+j)*27)*4096;
      k_sconv<<<NLT/16,256,0,stream>>>(fLcur, nbrL, kmaskL, Wc, fLalt, NLT);
      k_colsum<<<256,256,0,stream>>>(fLalt, NLT, partial);
      k_bnfin<<<1,64,0,stream>>>(partial, 256, 1.0f/NLT,
                                 bng + ((l*2+1)*3+j)*64, bnb + ((l*2+1)*3+j)*64, mv);
      k_bnrelu<<<(NLT*64+255)/256,256,0,stream>>>(fLalt, mv, NLT*64);
      float* tmp=fLcur; fLcur=fLalt; fLalt=tmp;
    }
    // image gate features for this layer
    k_imgf<<<1,128,0,stream>>>(img, Wimg + (size_t)l*512*64, bimg + l*64, imgfbuf);
    // attention + gated residual (in-place on fL)
    const int* knn = (l==0)? knn0 : knn1;
    int K = (l==0)? 64 : 32;
    k_attn<<<NLT,64,0,stream>>>(fLcur, fRcur, knn, coordsL,
                                Wval + (size_t)l*4096, bval + l*64,
                                Wgate + (size_t)l*8192, bgate + l*64,
                                imgfbuf, K);
    // BEV R (slab 2l) and BEV L (slab 2l+1)
    {
      float* op = outp + (size_t)(2*l)*64*16384;
      const float* wt = Wt2 + (size_t)(l*2+0)*9*16*4096;
      k_bev<<<2*128*128,64,0,stream>>>(fRcur, ccntR, centR, wt, op);
      k_bevstat<<<64,256,0,stream>>>(op, bntg + (l*2+0)*64, bntb + (l*2+0)*64, mv);
      k_bevbn<<<(2*64*16384+255)/256,256,0,stream>>>(op, mv);
    }
    {
      float* op = outp + (size_t)(2*l+1)*64*16384;
      const float* wt = Wt2 + (size_t)(l*2+1)*9*16*4096;
      k_bev<<<2*128*128,64,0,stream>>>(fLcur, ccntL, centL, wt, op);
      k_bevstat<<<64,256,0,stream>>>(op, bntg + (l*2+1)*64, bntb + (l*2+1)*64, mv);
      k_bevbn<<<(2*64*16384+255)/256,256,0,stream>>>(op, mv);
    }
  }
}